// Round 1
// baseline (131.030 us; speedup 1.0000x reference)
//
#include <hip/hip_runtime.h>
#include <stdint.h>

// ---------------------------------------------------------------------------
// NeighborSearch: data[n,3], queries[m,3], radius scalar.
// Out layout (int32): [0, m*n)   neighbors_index (compacted front, -1 pad)
//                     [m*n, m*n+m+1) row_splits (exclusive prefix of counts)
// ---------------------------------------------------------------------------

__device__ __forceinline__ float next_up(float x) {
    unsigned u = __float_as_uint(x);
    return __uint_as_float(u + 1u);
}
__device__ __forceinline__ float next_down(float x) {
    unsigned u = __float_as_uint(x);
    return __uint_as_float(u - 1u);
}

// Largest float T such that correctly-rounded sqrt(T) <= r  (r > 0).
// Then (u <= T) <=> (sqrt_rn(max(u,0)) <= r)  for all u (negatives included).
__device__ __forceinline__ float sq_threshold(float r) {
    float T = __fmul_rn(r, r);
    while (__fsqrt_rn(T) > r) T = next_down(T);
    while (__fsqrt_rn(next_up(T)) <= r) T = next_up(T);
    return T;
}

// Replicate reference arithmetic exactly (no contraction):
// q2 = (qx*qx + qy*qy) + qz*qz   (plain rounded ops)
// dot = fma(qz,dz, fma(qy,dy, qx*dx))  (BLAS/XLA K=3 fma chain)
// u = (q2 + d2) - 2*dot
__device__ __forceinline__ float pair_metric(float qx, float qy, float qz, float q2,
                                             float dx, float dy, float dz) {
    float d2 = __fadd_rn(__fadd_rn(__fmul_rn(dx, dx), __fmul_rn(dy, dy)),
                         __fmul_rn(dz, dz));
    float dot = __builtin_fmaf(qz, dz, __builtin_fmaf(qy, dy, __fmul_rn(qx, dx)));
    return __fsub_rn(__fadd_rn(q2, d2), __fmul_rn(2.0f, dot));
}

__global__ __launch_bounds__(256) void fill_kernel(int* __restrict__ out, size_t total) {
    size_t n4 = total >> 2;
    int4* out4 = (int4*)out;
    size_t i = (size_t)blockIdx.x * blockDim.x + threadIdx.x;
    size_t stride = (size_t)gridDim.x * blockDim.x;
    const int4 v = make_int4(-1, -1, -1, -1);
    for (; i < n4; i += stride) out4[i] = v;
    if (blockIdx.x == 0 && threadIdx.x == 0) {
        for (size_t k = n4 << 2; k < total; ++k) out[k] = -1;
    }
}

__global__ __launch_bounds__(256) void count_kernel(
    const float* __restrict__ data, const float* __restrict__ queries,
    const float* __restrict__ radius_p, int n, int m, int* __restrict__ counts) {
    int q = (blockIdx.x * blockDim.x + threadIdx.x) >> 6;
    int lane = threadIdx.x & 63;
    if (q >= m) return;
    float r = radius_p[0];
    float T = sq_threshold(r);
    float qx = queries[3 * q + 0], qy = queries[3 * q + 1], qz = queries[3 * q + 2];
    float q2 = __fadd_rn(__fadd_rn(__fmul_rn(qx, qx), __fmul_rn(qy, qy)),
                         __fmul_rn(qz, qz));
    int cnt = 0;
    for (int j = lane; j < n; j += 64) {
        float dx = data[3 * j + 0], dy = data[3 * j + 1], dz = data[3 * j + 2];
        float u = pair_metric(qx, qy, qz, q2, dx, dy, dz);
        if (u <= T) cnt++;
    }
    for (int off = 32; off > 0; off >>= 1) cnt += __shfl_down(cnt, off, 64);
    if (lane == 0) counts[q] = cnt;
}

// In-place: rs[0..m-1] hold counts; rewrite as exclusive prefix rs[0..m].
__global__ __launch_bounds__(1024) void scan_kernel(int* __restrict__ rs, int m) {
    __shared__ int part[1024];
    int t = threadIdx.x;
    int base = t * 8;
    int c[8];
    int s = 0;
    for (int k = 0; k < 8; ++k) {
        int p = base + k;
        c[k] = (p < m) ? rs[p] : 0;
        s += c[k];
    }
    part[t] = s;
    __syncthreads();
    for (int off = 1; off < 1024; off <<= 1) {
        int v = 0;
        if (t >= off) v = part[t - off];
        __syncthreads();
        if (t >= off) part[t] += v;
        __syncthreads();
    }
    int run = (t == 0) ? 0 : part[t - 1];
    for (int k = 0; k < 8; ++k) {
        int p = base + k;
        if (p < m) rs[p] = run;
        run += c[k];
    }
    if (t == 1023) rs[m] = part[1023];
}

__global__ __launch_bounds__(256) void emit_kernel(
    const float* __restrict__ data, const float* __restrict__ queries,
    const float* __restrict__ radius_p, int n, int m,
    const int* __restrict__ row_splits, int* __restrict__ out_idx) {
    int q = (blockIdx.x * blockDim.x + threadIdx.x) >> 6;
    int lane = threadIdx.x & 63;
    if (q >= m) return;
    float r = radius_p[0];
    float T = sq_threshold(r);
    float qx = queries[3 * q + 0], qy = queries[3 * q + 1], qz = queries[3 * q + 2];
    float q2 = __fadd_rn(__fadd_rn(__fmul_rn(qx, qx), __fmul_rn(qy, qy)),
                         __fmul_rn(qz, qz));
    int base = row_splits[q];
    unsigned long long lane_mask_lt = (lane == 0) ? 0ULL : (~0ULL >> (64 - lane));
    for (int j0 = 0; j0 < n; j0 += 64) {
        int j = j0 + lane;
        bool pred = false;
        if (j < n) {
            float dx = data[3 * j + 0], dy = data[3 * j + 1], dz = data[3 * j + 2];
            float u = pair_metric(qx, qy, qz, q2, dx, dy, dz);
            pred = (u <= T);
        }
        unsigned long long mask = __ballot(pred);
        if (pred) {
            int pos = base + __popcll(mask & lane_mask_lt);
            out_idx[pos] = j;
        }
        base += __popcll(mask);
    }
}

extern "C" void kernel_launch(void* const* d_in, const int* in_sizes, int n_in,
                              void* d_out, int out_size, void* d_ws, size_t ws_size,
                              hipStream_t stream) {
    const float* data = (const float*)d_in[0];
    const float* queries = (const float*)d_in[1];
    const float* radius = (const float*)d_in[2];
    int n = in_sizes[0] / 3;
    int m = in_sizes[1] / 3;
    int* out = (int*)d_out;
    size_t idx_count = (size_t)m * (size_t)n;
    int* row = out + idx_count;  // m+1 ints

    // 1) -1 fill of the index region (HBM-write-bound, ~43us floor)
    fill_kernel<<<2048, 256, 0, stream>>>(out, idx_count);

    // 2) per-query counts -> stored in-place in the row_splits slot
    int blocks = (m * 64 + 255) / 256;
    count_kernel<<<blocks, 256, 0, stream>>>(data, queries, radius, n, m, row);

    // 3) exclusive scan -> row_splits[0..m]
    scan_kernel<<<1, 1024, 0, stream>>>(row, m);

    // 4) ordered compacted emission of valid neighbor indices
    emit_kernel<<<blocks, 256, 0, stream>>>(data, queries, radius, n, m, row, out);
}

// Round 2
// 81.017 us; speedup vs baseline: 1.6173x; 1.6173x over previous
//
#include <hip/hip_runtime.h>
#include <stdint.h>

// ---------------------------------------------------------------------------
// NeighborSearch: data[n,3], queries[m,3], radius scalar.
// Out layout (int32): [0, m*n)   neighbors_index (compacted front, -1 pad)
//                     [m*n, m*n+m+1) row_splits (exclusive prefix of counts)
//
// Fast path (n==m==8192, ws >= 8.5MB):
//   K1 fused: even blocks -1-fill the index region (write-BW-bound),
//             odd blocks count + build per-query 64-bit chunk masks in d_ws
//             (VALU/LDS-bound) -> the two overlap on each CU.
//   K2 scan: exclusive prefix of counts -> row_splits.
//   K3 emit: read masks, wave prefix of popcounts, write compacted indices.
// ---------------------------------------------------------------------------

__device__ __forceinline__ float next_up(float x) {
    return __uint_as_float(__float_as_uint(x) + 1u);
}
__device__ __forceinline__ float next_down(float x) {
    return __uint_as_float(__float_as_uint(x) - 1u);
}

// Largest float T such that correctly-rounded sqrt(T) <= r (r > 0).
// (u <= T) <=> (sqrt_rn(max(u,0)) <= r) for all u, since sqrt_rn is monotone.
__device__ __forceinline__ float sq_threshold(float r) {
    float T = __fmul_rn(r, r);
    while (__fsqrt_rn(T) > r) T = next_down(T);
    while (__fsqrt_rn(next_up(T)) <= r) T = next_up(T);
    return T;
}

// Reference arithmetic, exactly (no contraction):
// d2 = (dx*dx + dy*dy) + dz*dz ; dot = fma(qz,dz, fma(qy,dy, qx*dx))
// u  = (q2 + d2) - 2*dot
__device__ __forceinline__ float pair_metric_d2(float qx, float qy, float qz,
                                                float q2, float dx, float dy,
                                                float dz, float d2) {
    float dot = __builtin_fmaf(qz, dz, __builtin_fmaf(qy, dy, __fmul_rn(qx, dx)));
    return __fsub_rn(__fadd_rn(q2, d2), __fmul_rn(2.0f, dot));
}
__device__ __forceinline__ float pair_metric(float qx, float qy, float qz, float q2,
                                             float dx, float dy, float dz) {
    float d2 = __fadd_rn(__fadd_rn(__fmul_rn(dx, dx), __fmul_rn(dy, dy)),
                         __fmul_rn(dz, dz));
    return pair_metric_d2(qx, qy, qz, q2, dx, dy, dz, d2);
}

// ========================= fast path (8192 x 8192) =========================

// Grid: 4096 blocks x 256 threads. Even blocks: fill role. Odd: count role.
__global__ __launch_bounds__(256) void fused_fill_count(
    const float* __restrict__ data, const float* __restrict__ queries,
    const float* __restrict__ radius_p, int* __restrict__ out_idx,
    unsigned long long* __restrict__ masks, int* __restrict__ counts) {
    constexpr int N = 8192;
    __shared__ float4 pts[512];

    int role = blockIdx.x & 1;
    int rb = blockIdx.x >> 1;

    if (role == 0) {
        // ---- fill role: -1 the whole index region (8192*8192 ints) ----
        int4* out4 = (int4*)out_idx;
        const size_t n4 = (size_t)N * N / 4;          // 16,777,216
        size_t i = (size_t)rb * 256 + threadIdx.x;
        const size_t stride = 2048ull * 256ull;
        const int4 v = make_int4(-1, -1, -1, -1);
        for (; i < n4; i += stride) out4[i] = v;
        return;
    }

    // ---- count role: wave = one query, lanes stride data chunks ----
    int wave = threadIdx.x >> 6;
    int lane = threadIdx.x & 63;
    int q = rb * 4 + wave;

    float r = radius_p[0];
    float T = sq_threshold(r);
    float qx = queries[3 * q + 0], qy = queries[3 * q + 1], qz = queries[3 * q + 2];
    float q2 = __fadd_rn(__fadd_rn(__fmul_rn(qx, qx), __fmul_rn(qy, qy)),
                         __fmul_rn(qz, qz));

    unsigned long long mlo = 0, mhi = 0;  // this wave's mask for chunk c is
    int cnt = 0;                          // parked in lane (c & 63)'s mlo/mhi

    for (int rd = 0; rd < 16; ++rd) {     // 16 rounds x 512 points
        int p0 = rd * 512;
        __syncthreads();
        for (int p = threadIdx.x; p < 512; p += 256) {
            float dx = data[3 * (p0 + p) + 0];
            float dy = data[3 * (p0 + p) + 1];
            float dz = data[3 * (p0 + p) + 2];
            float d2 = __fadd_rn(__fadd_rn(__fmul_rn(dx, dx), __fmul_rn(dy, dy)),
                                 __fmul_rn(dz, dz));
            pts[p] = make_float4(dx, dy, dz, d2);
        }
        __syncthreads();
#pragma unroll
        for (int cc = 0; cc < 8; ++cc) {
            float4 d = pts[cc * 64 + lane];
            float u = pair_metric_d2(qx, qy, qz, q2, d.x, d.y, d.z, d.w);
            unsigned long long mask = __ballot(u <= T);
            int c = rd * 8 + cc;
            if (lane == (c & 63)) {
                if (c < 64) mlo = mask; else mhi = mask;
            }
            cnt += __popcll(mask);
        }
    }
    masks[(size_t)q * 128 + lane] = mlo;        // coalesced 512B per wave
    masks[(size_t)q * 128 + 64 + lane] = mhi;
    if (lane == 0) counts[q] = cnt;
}

// Exclusive scan of counts[0..m) -> rs[0..m]. One block, m <= 8192.
__global__ __launch_bounds__(1024) void scan_kernel2(const int* __restrict__ counts,
                                                     int* __restrict__ rs, int m) {
    __shared__ int part[1024];
    int t = threadIdx.x;
    int base = t * 8;
    int c[8];
    int s = 0;
    for (int k = 0; k < 8; ++k) {
        int p = base + k;
        c[k] = (p < m) ? counts[p] : 0;
        s += c[k];
    }
    part[t] = s;
    __syncthreads();
    for (int off = 1; off < 1024; off <<= 1) {
        int v = 0;
        if (t >= off) v = part[t - off];
        __syncthreads();
        if (t >= off) part[t] += v;
        __syncthreads();
    }
    int run = (t == 0) ? 0 : part[t - 1];
    for (int k = 0; k < 8; ++k) {
        int p = base + k;
        if (p < m) rs[p] = run;
        run += c[k];
    }
    if (t == 1023) rs[m] = part[1023];
}

// Wave per query: read 128 chunk masks, prefix popcounts, write indices.
__global__ __launch_bounds__(256) void emit_from_masks(
    const unsigned long long* __restrict__ masks, const int* __restrict__ rs,
    int* __restrict__ out_idx) {
    int wave = threadIdx.x >> 6;
    int lane = threadIdx.x & 63;
    int q = blockIdx.x * 4 + wave;

    unsigned long long lo = masks[(size_t)q * 128 + lane];
    unsigned long long hi = masks[(size_t)q * 128 + 64 + lane];
    int plo = __popcll(lo), phi = __popcll(hi);
    int ilo = plo, ihi = phi;
    for (int off = 1; off < 64; off <<= 1) {
        int a = __shfl_up(ilo, off, 64);
        int b = __shfl_up(ihi, off, 64);
        if (lane >= off) { ilo += a; ihi += b; }
    }
    int total_lo = __shfl(ilo, 63, 64);
    int base = rs[q];
    int pos_lo = base + ilo - plo;
    int pos_hi = base + total_lo + ihi - phi;
    int jb_lo = lane * 64, jb_hi = (64 + lane) * 64;
    while (lo) {
        int b = __builtin_ctzll(lo);
        out_idx[pos_lo++] = jb_lo + b;
        lo &= lo - 1;
    }
    while (hi) {
        int b = __builtin_ctzll(hi);
        out_idx[pos_hi++] = jb_hi + b;
        hi &= hi - 1;
    }
}

// ====================== generic fallback (round-1 path) ======================

__global__ __launch_bounds__(256) void fill_kernel(int* __restrict__ out, size_t total) {
    size_t n4 = total >> 2;
    int4* out4 = (int4*)out;
    size_t i = (size_t)blockIdx.x * blockDim.x + threadIdx.x;
    size_t stride = (size_t)gridDim.x * blockDim.x;
    const int4 v = make_int4(-1, -1, -1, -1);
    for (; i < n4; i += stride) out4[i] = v;
    if (blockIdx.x == 0 && threadIdx.x == 0) {
        for (size_t k = n4 << 2; k < total; ++k) out[k] = -1;
    }
}

__global__ __launch_bounds__(256) void count_kernel(
    const float* __restrict__ data, const float* __restrict__ queries,
    const float* __restrict__ radius_p, int n, int m, int* __restrict__ counts) {
    int q = (blockIdx.x * blockDim.x + threadIdx.x) >> 6;
    int lane = threadIdx.x & 63;
    if (q >= m) return;
    float r = radius_p[0];
    float T = sq_threshold(r);
    float qx = queries[3 * q + 0], qy = queries[3 * q + 1], qz = queries[3 * q + 2];
    float q2 = __fadd_rn(__fadd_rn(__fmul_rn(qx, qx), __fmul_rn(qy, qy)),
                         __fmul_rn(qz, qz));
    int cnt = 0;
    for (int j = lane; j < n; j += 64) {
        float u = pair_metric(qx, qy, qz, q2, data[3 * j], data[3 * j + 1], data[3 * j + 2]);
        if (u <= T) cnt++;
    }
    for (int off = 32; off > 0; off >>= 1) cnt += __shfl_down(cnt, off, 64);
    if (lane == 0) counts[q] = cnt;
}

__global__ __launch_bounds__(256) void emit_kernel(
    const float* __restrict__ data, const float* __restrict__ queries,
    const float* __restrict__ radius_p, int n, int m,
    const int* __restrict__ row_splits, int* __restrict__ out_idx) {
    int q = (blockIdx.x * blockDim.x + threadIdx.x) >> 6;
    int lane = threadIdx.x & 63;
    if (q >= m) return;
    float r = radius_p[0];
    float T = sq_threshold(r);
    float qx = queries[3 * q + 0], qy = queries[3 * q + 1], qz = queries[3 * q + 2];
    float q2 = __fadd_rn(__fadd_rn(__fmul_rn(qx, qx), __fmul_rn(qy, qy)),
                         __fmul_rn(qz, qz));
    int base = row_splits[q];
    unsigned long long lane_mask_lt = (lane == 0) ? 0ULL : (~0ULL >> (64 - lane));
    for (int j0 = 0; j0 < n; j0 += 64) {
        int j = j0 + lane;
        bool pred = false;
        if (j < n) {
            float u = pair_metric(qx, qy, qz, q2, data[3 * j], data[3 * j + 1], data[3 * j + 2]);
            pred = (u <= T);
        }
        unsigned long long mask = __ballot(pred);
        if (pred) {
            int pos = base + __popcll(mask & lane_mask_lt);
            out_idx[pos] = j;
        }
        base += __popcll(mask);
    }
}

// ===========================================================================

extern "C" void kernel_launch(void* const* d_in, const int* in_sizes, int n_in,
                              void* d_out, int out_size, void* d_ws, size_t ws_size,
                              hipStream_t stream) {
    const float* data = (const float*)d_in[0];
    const float* queries = (const float*)d_in[1];
    const float* radius = (const float*)d_in[2];
    int n = in_sizes[0] / 3;
    int m = in_sizes[1] / 3;
    int* out = (int*)d_out;
    size_t idx_count = (size_t)m * (size_t)n;
    int* row = out + idx_count;  // m+1 ints

    size_t need = (size_t)m * 128 * 8 + (size_t)m * 4;
    bool fast = (n == 8192) && (m == 8192) && (ws_size >= need);

    if (fast) {
        unsigned long long* masks = (unsigned long long*)d_ws;
        int* counts = (int*)((char*)d_ws + (size_t)m * 128 * 8);
        // 2048 fill blocks + 2048 count blocks, interleaved by parity
        fused_fill_count<<<4096, 256, 0, stream>>>(data, queries, radius, out,
                                                   masks, counts);
        scan_kernel2<<<1, 1024, 0, stream>>>(counts, row, m);
        emit_from_masks<<<m / 4, 256, 0, stream>>>(masks, row, out);
    } else {
        fill_kernel<<<2048, 256, 0, stream>>>(out, idx_count);
        int blocks = (m * 64 + 255) / 256;
        count_kernel<<<blocks, 256, 0, stream>>>(data, queries, radius, n, m, row);
        scan_kernel2<<<1, 1024, 0, stream>>>(row, row, m);
        emit_kernel<<<blocks, 256, 0, stream>>>(data, queries, radius, n, m, row, out);
    }
}